// Round 1
// baseline (874.603 us; speedup 1.0000x reference)
//
#include <hip/hip_runtime.h>

#define N2   8192
#define N    4096
#define LOGN 12
#define F_TOT 4097   // N2/2 + 1
#define D    128
#define K    16
#define B    2
#define FT   16      // f-values per middle-kernel block

// In-place radix-2 DIT FFT on bit-reverse-loaded data in LDS.
// sign = -1 forward, +1 inverse (unnormalized).
__device__ __forceinline__ void fft_lds(float* re, float* im, int tid, int nthr, float sign) {
  for (int s = 0; s < LOGN; ++s) {
    int len = 1 << s;
    for (int t = tid; t < (N >> 1); t += nthr) {
      int j = t & (len - 1);
      int base = ((t >> s) << (s + 1)) + j;
      float ang = sign * 3.14159265358979323846f * (float)j / (float)len;
      float wi, wr;
      __sincosf(ang, &wi, &wr);
      float ar = re[base], ai = im[base];
      float br = re[base + len], bi = im[base + len];
      float tr = wr * br - wi * bi;
      float ti = wr * bi + wi * br;
      re[base] = ar + tr;       im[base] = ai + ti;
      re[base + len] = ar - tr; im[base + len] = ai - ti;
    }
    __syncthreads();
  }
}

// Forward rfft(n=8192) of a real length-4096 signal via 4096-pt complex FFT.
// blocks 0..255: x signals (b,d).  blocks 256..271: filter signals (k).
__global__ __launch_bounds__(256) void fwd_fft(const float* __restrict__ x,
                                               const float* __restrict__ filt,
                                               float2* __restrict__ Uf,
                                               float2* __restrict__ Vf) {
  __shared__ float re[N];
  __shared__ float im[N];
  const int tid = threadIdx.x;
  const int sig = blockIdx.x;
  const float* in; int istride; float2* outp; int ostride;
  if (sig < B * D) {
    int b = sig >> 7, d = sig & (D - 1);
    in = x + (size_t)b * N * D + d;              istride = D;
    outp = Uf + (size_t)b * F_TOT * D + d;       ostride = D;
  } else {
    int k = sig - B * D;
    in = filt + k;                               istride = K;
    outp = Vf + k;                               ostride = K;
  }
  // load z[m] = in[2m] + i*in[2m+1] (m<2048), zero-padded; bit-reversed placement
  for (int i = tid; i < N; i += 256) {
    int m = __brev(i) >> (32 - LOGN);
    float vr = 0.f, vi = 0.f;
    if (m < (N >> 1)) {
      vr = in[(size_t)(2 * m) * istride];
      vi = in[(size_t)(2 * m + 1) * istride];
    }
    re[i] = vr; im[i] = vi;
  }
  __syncthreads();
  fft_lds(re, im, tid, 256, -1.0f);
  // real-FFT recombination: X[f] = E[f] + e^{-i pi f/N} O[f], f = 0..N
  for (int f = tid; f <= N; f += 256) {
    int f2 = f & (N - 1);
    int fn = (N - f) & (N - 1);
    float zr = re[f2], zi = im[f2];
    float nr = re[fn], ni = im[fn];
    float Er = 0.5f * (zr + nr), Ei = 0.5f * (zi - ni);
    float Or = 0.5f * (zi + ni), Oi = -0.5f * (zr - nr);
    float ang = -3.14159265358979323846f * (float)f / (float)N;
    float wi, wr; __sincosf(ang, &wi, &wr);
    float Xr = Er + wr * Or - wi * Oi;
    float Xi = Ei + wr * Oi + wi * Or;
    outp[(size_t)f * ostride] = make_float2(Xr, Xi);
  }
}

// G[b,f,e] = sum_d Uf[b,f,d] * ( sum_k Vf[f,k] Mp[k,d,e] + conj(Vf[N-f,k]) Mm[k,d,e] )
__global__ __launch_bounds__(128) void middle(const float2* __restrict__ Uf,
                                              const float2* __restrict__ Vf,
                                              const float* __restrict__ Mp,
                                              const float* __restrict__ Mm,
                                              float2* __restrict__ G) {
  __shared__ __align__(16) float2 u[FT][D];
  const int e  = threadIdx.x;
  const int b  = blockIdx.y;
  const int f0 = blockIdx.x * FT;
  for (int i = e; i < FT * D; i += 128) {
    int j = i >> 7, d = i & (D - 1);
    int f = f0 + j;
    float2 v = make_float2(0.f, 0.f);
    if (f < F_TOT) v = Uf[((size_t)b * F_TOT + f) * D + d];
    u[j][d] = v;
  }
  __syncthreads();

  float Gx[FT], Gy[FT];
#pragma unroll
  for (int j = 0; j < FT; ++j) { Gx[j] = 0.f; Gy[j] = 0.f; }

  for (int k = 0; k < K; ++k) {
    float tpx[FT], tpy[FT], tmx[FT], tmy[FT];
#pragma unroll
    for (int j = 0; j < FT; ++j) { tpx[j] = 0.f; tpy[j] = 0.f; tmx[j] = 0.f; tmy[j] = 0.f; }
    const float* mpk = Mp + (size_t)k * D * D + e;
    const float* mmk = Mm + (size_t)k * D * D + e;
    for (int d = 0; d < D; d += 2) {
      float mp0 = mpk[(size_t)d * D],       mm0 = mmk[(size_t)d * D];
      float mp1 = mpk[(size_t)(d + 1) * D], mm1 = mmk[(size_t)(d + 1) * D];
#pragma unroll
      for (int j = 0; j < FT; ++j) {
        float4 uu = *(const float4*)&u[j][d];   // (re,im) of u[j][d] and u[j][d+1]
        tpx[j] = fmaf(uu.z, mp1, fmaf(uu.x, mp0, tpx[j]));
        tpy[j] = fmaf(uu.w, mp1, fmaf(uu.y, mp0, tpy[j]));
        tmx[j] = fmaf(uu.z, mm1, fmaf(uu.x, mm0, tmx[j]));
        tmy[j] = fmaf(uu.w, mm1, fmaf(uu.y, mm0, tmy[j]));
      }
    }
#pragma unroll
    for (int j = 0; j < FT; ++j) {
      int f = f0 + j;
      if (f < F_TOT) {
        float2 vp = Vf[(size_t)f * K + k];
        float2 vr = Vf[(size_t)(N - f) * K + k];
        float vry = -vr.y;  // conj
        Gx[j] += vp.x * tpx[j] - vp.y * tpy[j] + vr.x * tmx[j] - vry * tmy[j];
        Gy[j] += vp.x * tpy[j] + vp.y * tpx[j] + vr.x * tmy[j] + vry * tmx[j];
      }
    }
  }
#pragma unroll
  for (int j = 0; j < FT; ++j) {
    int f = f0 + j;
    if (f < F_TOT) G[((size_t)b * F_TOT + f) * D + e] = make_float2(Gx[j], Gy[j]);
  }
}

// irfft(n=8192) of G[b,:,e], keep first 4096 samples -> out[b,:,e]
__global__ __launch_bounds__(256) void inv_fft(const float2* __restrict__ G,
                                               float* __restrict__ out) {
  __shared__ float re[N];
  __shared__ float im[N];
  const int tid = threadIdx.x;
  const int sig = blockIdx.x;
  const int b = sig >> 7, e = sig & (D - 1);
  const float2* Gb = G + (size_t)b * F_TOT * D + e;
  for (int kk = tid; kk < N; kk += 256) {
    float2 Xk = Gb[(size_t)kk * D];
    float2 Xn = Gb[(size_t)(N - kk) * D];
    float cr = Xn.x, ci = -Xn.y;                 // conj(X[N-k])
    float Er = 0.5f * (Xk.x + cr), Ei = 0.5f * (Xk.y + ci);
    float Dr = 0.5f * (Xk.x - cr), Di = 0.5f * (Xk.y - ci);
    float ang = 3.14159265358979323846f * (float)kk / (float)N;
    float wi, wr; __sincosf(ang, &wi, &wr);
    float Or = Dr * wr - Di * wi;
    float Oi = Dr * wi + Di * wr;
    float Zr = Er - Oi, Zi = Ei + Or;            // Z = E + i*O
    int dst = __brev(kk) >> (32 - LOGN);
    re[dst] = Zr; im[dst] = Zi;
  }
  __syncthreads();
  fft_lds(re, im, tid, 256, +1.0f);
  const float scale = 1.0f / (float)N;
  float* ob = out + (size_t)b * N * D + e;
  for (int m = tid; m < (N >> 1); m += 256) {
    ob[(size_t)(2 * m) * D]     = re[m] * scale;
    ob[(size_t)(2 * m + 1) * D] = im[m] * scale;
  }
}

extern "C" void kernel_launch(void* const* d_in, const int* in_sizes, int n_in,
                              void* d_out, int out_size, void* d_ws, size_t ws_size,
                              hipStream_t stream) {
  const float* x  = (const float*)d_in[0];
  const float* fl = (const float*)d_in[1];
  const float* Mp = (const float*)d_in[2];
  const float* Mm = (const float*)d_in[3];
  float* out = (float*)d_out;

  float2* Uf = (float2*)d_ws;                       // (B, F_TOT, D)
  float2* Vf = Uf + (size_t)B * F_TOT * D;          // (F_TOT, K)
  float2* G  = Vf + (size_t)F_TOT * K;              // (B, F_TOT, D)

  fwd_fft<<<B * D + K, 256, 0, stream>>>(x, fl, Uf, Vf);
  middle<<<dim3((F_TOT + FT - 1) / FT, B), 128, 0, stream>>>(Uf, Vf, Mp, Mm, G);
  inv_fft<<<B * D, 256, 0, stream>>>(G, out);
}

// Round 2
// 859.359 us; speedup vs baseline: 1.0177x; 1.0177x over previous
//
#include <hip/hip_runtime.h>

#define N2   8192
#define N    4096
#define LOGN 12
#define F_TOT 4097   // N2/2 + 1
#define D    128
#define K    16
#define B    2

// In-place radix-2 DIT FFT on bit-reverse-loaded data in LDS.
// sign = -1 forward, +1 inverse (unnormalized).
__device__ __forceinline__ void fft_lds(float* re, float* im, int tid, int nthr, float sign) {
  for (int s = 0; s < LOGN; ++s) {
    int len = 1 << s;
    for (int t = tid; t < (N >> 1); t += nthr) {
      int j = t & (len - 1);
      int base = ((t >> s) << (s + 1)) + j;
      float ang = sign * 3.14159265358979323846f * (float)j / (float)len;
      float wi, wr;
      __sincosf(ang, &wi, &wr);
      float ar = re[base], ai = im[base];
      float br = re[base + len], bi = im[base + len];
      float tr = wr * br - wi * bi;
      float ti = wr * bi + wi * br;
      re[base] = ar + tr;       im[base] = ai + ti;
      re[base + len] = ar - tr; im[base + len] = ai - ti;
    }
    __syncthreads();
  }
}

// Forward rfft(n=8192) of a real length-4096 signal via 4096-pt complex FFT.
// blocks 0..255: x signals (b,d).  blocks 256..271: filter signals (k).
__global__ __launch_bounds__(256) void fwd_fft(const float* __restrict__ x,
                                               const float* __restrict__ filt,
                                               float2* __restrict__ Uf,
                                               float2* __restrict__ Vf) {
  __shared__ float re[N];
  __shared__ float im[N];
  const int tid = threadIdx.x;
  const int sig = blockIdx.x;
  const float* in; int istride; float2* outp; int ostride;
  if (sig < B * D) {
    int b = sig >> 7, d = sig & (D - 1);
    in = x + (size_t)b * N * D + d;              istride = D;
    outp = Uf + (size_t)b * F_TOT * D + d;       ostride = D;
  } else {
    int k = sig - B * D;
    in = filt + k;                               istride = K;
    outp = Vf + k;                               ostride = K;
  }
  // load z[m] = in[2m] + i*in[2m+1] (m<2048), zero-padded; bit-reversed placement
  for (int i = tid; i < N; i += 256) {
    int m = __brev(i) >> (32 - LOGN);
    float vr = 0.f, vi = 0.f;
    if (m < (N >> 1)) {
      vr = in[(size_t)(2 * m) * istride];
      vi = in[(size_t)(2 * m + 1) * istride];
    }
    re[i] = vr; im[i] = vi;
  }
  __syncthreads();
  fft_lds(re, im, tid, 256, -1.0f);
  // real-FFT recombination: X[f] = E[f] + e^{-i pi f/N} O[f], f = 0..N
  for (int f = tid; f <= N; f += 256) {
    int f2 = f & (N - 1);
    int fn = (N - f) & (N - 1);
    float zr = re[f2], zi = im[f2];
    float nr = re[fn], ni = im[fn];
    float Er = 0.5f * (zr + nr), Ei = 0.5f * (zi - ni);
    float Or = 0.5f * (zi + ni), Oi = -0.5f * (zr - nr);
    float ang = -3.14159265358979323846f * (float)f / (float)N;
    float wi, wr; __sincosf(ang, &wi, &wr);
    float Xr = Er + wr * Or - wi * Oi;
    float Xi = Ei + wr * Oi + wi * Or;
    outp[(size_t)f * ostride] = make_float2(Xr, Xi);
  }
}

// G[b,f,e] = sum_d Uf[b,f,d] * ( sum_k Vf[f,k] Mp[k,d,e] + conj(Vf[N-f,k]) Mm[k,d,e] )
//
// Block = 256 threads: e = tid&127, half q = tid>>7. Each half owns 8 f's
// (f0 = bx*16 + q*8 + j). 48 fp32 accumulators/thread (fits registers, no
// fission). u rows are lane-uniform broadcast float4 loads from global (L1);
// M rows are coalesced dword loads (L2-resident, each feeds 16 FMA).
__global__ __launch_bounds__(256) void middle(const float2* __restrict__ Uf,
                                              const float2* __restrict__ Vf,
                                              const float* __restrict__ Mp,
                                              const float* __restrict__ Mm,
                                              float2* __restrict__ G) {
  const int e  = threadIdx.x & (D - 1);
  const int q  = threadIdx.x >> 7;
  const int b  = blockIdx.y;
  const int f0 = blockIdx.x * 16 + q * 8;

  const float4* uptr[8];
#pragma unroll
  for (int j = 0; j < 8; ++j) {
    int f = f0 + j; if (f > N) f = N;   // clamp: garbage rows computed but never combined/written
    uptr[j] = (const float4*)(Uf + ((size_t)b * F_TOT + f) * D);
  }

  float Gx[8], Gy[8];
#pragma unroll
  for (int j = 0; j < 8; ++j) { Gx[j] = 0.f; Gy[j] = 0.f; }

  for (int k = 0; k < K; ++k) {
    float tpx[8], tpy[8], tmx[8], tmy[8];
#pragma unroll
    for (int j = 0; j < 8; ++j) { tpx[j] = 0.f; tpy[j] = 0.f; tmx[j] = 0.f; tmy[j] = 0.f; }

    const float* mpk = Mp + (size_t)k * D * D + e;
    const float* mmk = Mm + (size_t)k * D * D + e;

    for (int d = 0; d < D; d += 4) {
      const float* mpd = mpk + (size_t)d * D;
      const float* mmd = mmk + (size_t)d * D;
      float mp0 = mpd[0],     mm0 = mmd[0];
      float mp1 = mpd[D],     mm1 = mmd[D];
      float mp2 = mpd[2 * D], mm2 = mmd[2 * D];
      float mp3 = mpd[3 * D], mm3 = mmd[3 * D];
#pragma unroll
      for (int j = 0; j < 8; ++j) {
        float4 u0 = uptr[j][(d >> 1)];       // (re,im) of d, d+1
        float4 u1 = uptr[j][(d >> 1) + 1];   // (re,im) of d+2, d+3
        tpx[j] = fmaf(u1.z, mp3, fmaf(u1.x, mp2, fmaf(u0.z, mp1, fmaf(u0.x, mp0, tpx[j]))));
        tpy[j] = fmaf(u1.w, mp3, fmaf(u1.y, mp2, fmaf(u0.w, mp1, fmaf(u0.y, mp0, tpy[j]))));
        tmx[j] = fmaf(u1.z, mm3, fmaf(u1.x, mm2, fmaf(u0.z, mm1, fmaf(u0.x, mm0, tmx[j]))));
        tmy[j] = fmaf(u1.w, mm3, fmaf(u1.y, mm2, fmaf(u0.w, mm1, fmaf(u0.y, mm0, tmy[j]))));
      }
    }

#pragma unroll
    for (int j = 0; j < 8; ++j) {
      int f = f0 + j;
      if (f < F_TOT) {
        float2 vp = Vf[(size_t)f * K + k];
        float2 vr = Vf[(size_t)(N - f) * K + k];
        Gx[j] += vp.x * tpx[j] - vp.y * tpy[j] + vr.x * tmx[j] + vr.y * tmy[j];
        Gy[j] += vp.x * tpy[j] + vp.y * tpx[j] + vr.x * tmy[j] - vr.y * tmx[j];
      }
    }
  }

#pragma unroll
  for (int j = 0; j < 8; ++j) {
    int f = f0 + j;
    if (f < F_TOT) G[((size_t)b * F_TOT + f) * D + e] = make_float2(Gx[j], Gy[j]);
  }
}

// irfft(n=8192) of G[b,:,e], keep first 4096 samples -> out[b,:,e]
__global__ __launch_bounds__(256) void inv_fft(const float2* __restrict__ G,
                                               float* __restrict__ out) {
  __shared__ float re[N];
  __shared__ float im[N];
  const int tid = threadIdx.x;
  const int sig = blockIdx.x;
  const int b = sig >> 7, e = sig & (D - 1);
  const float2* Gb = G + (size_t)b * F_TOT * D + e;
  for (int kk = tid; kk < N; kk += 256) {
    float2 Xk = Gb[(size_t)kk * D];
    float2 Xn = Gb[(size_t)(N - kk) * D];
    float cr = Xn.x, ci = -Xn.y;                 // conj(X[N-k])
    float Er = 0.5f * (Xk.x + cr), Ei = 0.5f * (Xk.y + ci);
    float Dr = 0.5f * (Xk.x - cr), Di = 0.5f * (Xk.y - ci);
    float ang = 3.14159265358979323846f * (float)kk / (float)N;
    float wi, wr; __sincosf(ang, &wi, &wr);
    float Or = Dr * wr - Di * wi;
    float Oi = Dr * wi + Di * wr;
    float Zr = Er - Oi, Zi = Ei + Or;            // Z = E + i*O
    int dst = __brev(kk) >> (32 - LOGN);
    re[dst] = Zr; im[dst] = Zi;
  }
  __syncthreads();
  fft_lds(re, im, tid, 256, +1.0f);
  const float scale = 1.0f / (float)N;
  float* ob = out + (size_t)b * N * D + e;
  for (int m = tid; m < (N >> 1); m += 256) {
    ob[(size_t)(2 * m) * D]     = re[m] * scale;
    ob[(size_t)(2 * m + 1) * D] = im[m] * scale;
  }
}

extern "C" void kernel_launch(void* const* d_in, const int* in_sizes, int n_in,
                              void* d_out, int out_size, void* d_ws, size_t ws_size,
                              hipStream_t stream) {
  const float* x  = (const float*)d_in[0];
  const float* fl = (const float*)d_in[1];
  const float* Mp = (const float*)d_in[2];
  const float* Mm = (const float*)d_in[3];
  float* out = (float*)d_out;

  float2* Uf = (float2*)d_ws;                       // (B, F_TOT, D)
  float2* Vf = Uf + (size_t)B * F_TOT * D;          // (F_TOT, K)
  float2* G  = Vf + (size_t)F_TOT * K;              // (B, F_TOT, D)

  fwd_fft<<<B * D + K, 256, 0, stream>>>(x, fl, Uf, Vf);
  middle<<<dim3(257, B), 256, 0, stream>>>(Uf, Vf, Mp, Mm, G);
  inv_fft<<<B * D, 256, 0, stream>>>(G, out);
}

// Round 3
// 233.103 us; speedup vs baseline: 3.7520x; 3.6866x over previous
//
#include <hip/hip_runtime.h>

#define N2   8192
#define N    4096
#define LOGN 12
#define F_TOT 4097   // N2/2 + 1
#define D    128
#define K    16
#define B    2
#define KD   (K * D)   // 2048: flattened (k,d) per half
#define PI_F 3.14159265358979323846f

typedef __bf16 bf16x8 __attribute__((ext_vector_type(8)));
typedef float  f32x4  __attribute__((ext_vector_type(4)));

// In-place radix-2 DIT FFT on bit-reverse-loaded data in LDS.
__device__ __forceinline__ void fft_lds(float* re, float* im, int tid, int nthr, float sign) {
  for (int s = 0; s < LOGN; ++s) {
    int len = 1 << s;
    for (int t = tid; t < (N >> 1); t += nthr) {
      int j = t & (len - 1);
      int base = ((t >> s) << (s + 1)) + j;
      float ang = sign * PI_F * (float)j / (float)len;
      float wi, wr;
      __sincosf(ang, &wi, &wr);
      float ar = re[base], ai = im[base];
      float br = re[base + len], bi = im[base + len];
      float tr = wr * br - wi * bi;
      float ti = wr * bi + wi * br;
      re[base] = ar + tr;       im[base] = ai + ti;
      re[base + len] = ar - tr; im[base + len] = ai - ti;
    }
    __syncthreads();
  }
}

// Forward rfft(n=8192) of real length-4096 signals (x rows, filter cols) via
// 4096-pt complex FFT. Blocks 0..255: x (b,d). 256..271: filters (k).
// Blocks 272..303: M transpose+bf16 convert -> Mt[half][e][k*128+d].
__global__ __launch_bounds__(256) void fwd_fft(const float* __restrict__ x,
                                               const float* __restrict__ filt,
                                               const float* __restrict__ Mp,
                                               const float* __restrict__ Mm,
                                               float2* __restrict__ Uf,
                                               float2* __restrict__ Vf,
                                               __bf16* __restrict__ Mt) {
  __shared__ float re[N];
  __shared__ float im[N];
  const int tid = threadIdx.x;
  const int sig = blockIdx.x;

  if (sig >= B * D + K) {          // ---- M prep path ----
    const int pid = sig - (B * D + K);
    const int k = pid & 15, h = pid >> 4;
    const float* src = (h ? Mm : Mp) + (size_t)k * D * D;
    __bf16* dst = Mt + (size_t)h * D * KD;
    for (int d0 = 0; d0 < D; d0 += 16) {
      for (int i = tid; i < 16 * D; i += 256) re[i] = src[(size_t)d0 * D + i];
      __syncthreads();
      const int e = tid >> 1, c0 = (tid & 1) * 8;
      bf16x8 w;
#pragma unroll
      for (int j = 0; j < 8; ++j) w[j] = (__bf16)re[(c0 + j) * D + e];
      *(bf16x8*)(dst + (size_t)e * KD + k * D + d0 + c0) = w;
      __syncthreads();
    }
    return;
  }

  const float* in; int istride; float2* outp; int ostride;
  if (sig < B * D) {
    int b = sig >> 7, d = sig & (D - 1);
    in = x + (size_t)b * N * D + d;              istride = D;
    outp = Uf + (size_t)b * F_TOT * D + d;       ostride = D;
  } else {
    int k = sig - B * D;
    in = filt + k;                               istride = K;
    outp = Vf + k;                               ostride = K;
  }
  for (int i = tid; i < N; i += 256) {
    int m = __brev(i) >> (32 - LOGN);
    float vr = 0.f, vi = 0.f;
    if (m < (N >> 1)) {
      vr = in[(size_t)(2 * m) * istride];
      vi = in[(size_t)(2 * m + 1) * istride];
    }
    re[i] = vr; im[i] = vi;
  }
  __syncthreads();
  fft_lds(re, im, tid, 256, -1.0f);
  for (int f = tid; f <= N; f += 256) {
    int f2 = f & (N - 1);
    int fn = (N - f) & (N - 1);
    float zr = re[f2], zi = im[f2];
    float nr = re[fn], ni = im[fn];
    float Er = 0.5f * (zr + nr), Ei = 0.5f * (zi - ni);
    float Or = 0.5f * (zi + ni), Oi = -0.5f * (zr - nr);
    float ang = -PI_F * (float)f / (float)N;
    float wi, wr; __sincosf(ang, &wi, &wr);
    outp[(size_t)f * ostride] = make_float2(Er + wr * Or - wi * Oi,
                                            Ei + wr * Oi + wi * Or);
  }
}

// MFMA middle: rows r = f*4 + b*2 + comp (comp: 0=re 1=im).
// Wave = 32 rows (8 f) x 128 cols. Block = 4 waves = 32 f. Grid (128, half, ks).
// A[(row), kd] = coeff(V) dot U built in registers; B from Mt (bf16, [e][kd]).
__global__ __launch_bounds__(256, 2) void middle_mfma(const float2* __restrict__ Uf,
                                                      const float2* __restrict__ Vf,
                                                      const __bf16* __restrict__ Mt,
                                                      float2* __restrict__ Gp,
                                                      int nks) {
  const int tid = threadIdx.x;
  const int l = tid & 63, wave = tid >> 6;
  const int half = blockIdx.y, ks = blockIdx.z;
  const int fw0 = blockIdx.x * 32 + wave * 8;
  const int rowsub = l & 15, g = l >> 4;
  const int fo = rowsub >> 2, bb = (rowsub >> 1) & 1, comp = rowsub & 1;
  const int f0s = fw0 + fo;          // subtile 0 f
  const int f1s = f0s + 4;           // subtile 1 f

  const float4* u0p = (const float4*)(Uf + ((size_t)bb * F_TOT + f0s) * D);
  const float4* u1p = (const float4*)(Uf + ((size_t)bb * F_TOT + f1s) * D);
  const float2* v0p = Vf + (size_t)(half ? N - f0s : f0s) * K;
  const float2* v1p = Vf + (size_t)(half ? N - f1s : f1s) * K;
  const float vsgn = half ? -1.f : 1.f;
  const __bf16* mtb = Mt + (size_t)half * D * KD + (size_t)rowsub * KD;

  f32x4 acc[2][8];
#pragma unroll
  for (int s = 0; s < 2; ++s)
#pragma unroll
    for (int nt = 0; nt < 8; ++nt) acc[s][nt] = (f32x4)0.f;

  const int nk = K / nks;
  for (int k8 = 0; k8 < nk; ++k8) {
    const int k = ks * nk + k8;
    float2 v0 = v0p[k], v1 = v1p[k];
    float vi0 = vsgn * v0.y, vi1 = vsgn * v1.y;
    // a = c0*Ur + c1*Ui ; re: (vr, -vi)  im: (vi, vr)
    const float c00 = comp ? vi0 : v0.x;
    const float c01 = comp ? v0.x : -vi0;
    const float c10 = comp ? vi1 : v1.x;
    const float c11 = comp ? v1.x : -vi1;
#pragma unroll
    for (int ds = 0; ds < 4; ++ds) {
      const int q = ds * 16 + g * 4;     // float4 index: d0 = ds*32 + g*8 complex
      float4 ua = u0p[q], ub = u0p[q + 1], uc = u0p[q + 2], ud = u0p[q + 3];
      bf16x8 a0, a1;
      a0[0] = (__bf16)fmaf(c01, ua.y, c00 * ua.x);
      a0[1] = (__bf16)fmaf(c01, ua.w, c00 * ua.z);
      a0[2] = (__bf16)fmaf(c01, ub.y, c00 * ub.x);
      a0[3] = (__bf16)fmaf(c01, ub.w, c00 * ub.z);
      a0[4] = (__bf16)fmaf(c01, uc.y, c00 * uc.x);
      a0[5] = (__bf16)fmaf(c01, uc.w, c00 * uc.z);
      a0[6] = (__bf16)fmaf(c01, ud.y, c00 * ud.x);
      a0[7] = (__bf16)fmaf(c01, ud.w, c00 * ud.z);
      ua = u1p[q]; ub = u1p[q + 1]; uc = u1p[q + 2]; ud = u1p[q + 3];
      a1[0] = (__bf16)fmaf(c11, ua.y, c10 * ua.x);
      a1[1] = (__bf16)fmaf(c11, ua.w, c10 * ua.z);
      a1[2] = (__bf16)fmaf(c11, ub.y, c10 * ub.x);
      a1[3] = (__bf16)fmaf(c11, ub.w, c10 * ub.z);
      a1[4] = (__bf16)fmaf(c11, uc.y, c10 * uc.x);
      a1[5] = (__bf16)fmaf(c11, uc.w, c10 * uc.z);
      a1[6] = (__bf16)fmaf(c11, ud.y, c10 * ud.x);
      a1[7] = (__bf16)fmaf(c11, ud.w, c10 * ud.z);
      const __bf16* bp = mtb + k * D + ds * 32 + g * 8;
#pragma unroll
      for (int nt = 0; nt < 8; ++nt) {
        bf16x8 bf = *(const bf16x8*)(bp + (size_t)nt * 16 * KD);
        acc[0][nt] = __builtin_amdgcn_mfma_f32_16x16x32_bf16(a0, bf, acc[0][nt], 0, 0, 0);
        acc[1][nt] = __builtin_amdgcn_mfma_f32_16x16x32_bf16(a1, bf, acc[1][nt], 0, 0, 0);
      }
    }
  }

  // C layout: col = lane&15, row16 = g*4 + i  ->  f = fw0 + s*4 + g,
  // b_out = (i>>1)&1, comp_out = i&1. i pairs (0,1)/(2,3) form float2 stores.
  const int part = half * nks + ks;
#pragma unroll
  for (int s = 0; s < 2; ++s) {
    const int fst = fw0 + s * 4 + g;
#pragma unroll
    for (int nt = 0; nt < 8; ++nt) {
      const int e = nt * 16 + rowsub;
      Gp[(((size_t)part * B + 0) * F_TOT + fst) * D + e] = make_float2(acc[s][nt][0], acc[s][nt][1]);
      Gp[(((size_t)part * B + 1) * F_TOT + fst) * D + e] = make_float2(acc[s][nt][2], acc[s][nt][3]);
    }
  }
}

// irfft(n=8192): sums nslab partial G slabs; computes the single f=4096 value
// (needed only at kk==0) in fp32 as a block-cooperative reduction.
__global__ __launch_bounds__(256) void inv_fft(const float2* __restrict__ Gp,
                                               const float2* __restrict__ Uf,
                                               const float2* __restrict__ Vf,
                                               const float* __restrict__ Mp,
                                               const float* __restrict__ Mm,
                                               float* __restrict__ out, int nslab) {
  __shared__ float re[N];
  __shared__ float im[N];
  __shared__ float2 g4s;
  const int tid = threadIdx.x;
  const int sig = blockIdx.x;
  const int b = sig >> 7, e = sig & (D - 1);

  // phase 0: G[b, 4096, e] = sum_kd (Vp*U)*Mp + (conj(Vm)*U)*Mm  at f=4096
  {
    const float2* u4 = Uf + ((size_t)b * F_TOT + N) * D;
    float gx = 0.f, gy = 0.f;
    for (int i = tid; i < KD; i += 256) {
      const int k = i >> 7, d = i & (D - 1);
      float2 u = u4[d];
      float2 vp = Vf[(size_t)N * K + k];
      float2 vm = Vf[k];
      float mp = Mp[(size_t)k * D * D + (size_t)d * D + e];
      float mm = Mm[(size_t)k * D * D + (size_t)d * D + e];
      gx += (vp.x * u.x - vp.y * u.y) * mp + (vm.x * u.x + vm.y * u.y) * mm;
      gy += (vp.x * u.y + vp.y * u.x) * mp + (vm.x * u.y - vm.y * u.x) * mm;
    }
    re[tid] = gx; im[tid] = gy;
    __syncthreads();
    for (int s = 128; s > 0; s >>= 1) {
      if (tid < s) { re[tid] += re[tid + s]; im[tid] += im[tid + s]; }
      __syncthreads();
    }
    if (tid == 0) g4s = make_float2(re[0], im[0]);
    __syncthreads();
  }

  const float2* Gb = Gp + (size_t)b * F_TOT * D + e;
  const size_t slab = (size_t)B * F_TOT * D;
  for (int kk = tid; kk < N; kk += 256) {
    float2 Xk = make_float2(0.f, 0.f), Xn = make_float2(0.f, 0.f);
    for (int p = 0; p < nslab; ++p) {
      float2 t = Gb[p * slab + (size_t)kk * D];
      Xk.x += t.x; Xk.y += t.y;
    }
    if (kk == 0) Xn = g4s;
    else for (int p = 0; p < nslab; ++p) {
      float2 t = Gb[p * slab + (size_t)(N - kk) * D];
      Xn.x += t.x; Xn.y += t.y;
    }
    float cr = Xn.x, ci = -Xn.y;
    float Er = 0.5f * (Xk.x + cr), Ei = 0.5f * (Xk.y + ci);
    float Dr = 0.5f * (Xk.x - cr), Di = 0.5f * (Xk.y - ci);
    float ang = PI_F * (float)kk / (float)N;
    float wi, wr; __sincosf(ang, &wi, &wr);
    float Or = Dr * wr - Di * wi;
    float Oi = Dr * wi + Di * wr;
    int dst = __brev(kk) >> (32 - LOGN);
    re[dst] = Er - Oi; im[dst] = Ei + Or;
  }
  __syncthreads();
  fft_lds(re, im, tid, 256, +1.0f);
  const float scale = 1.0f / (float)N;
  float* ob = out + (size_t)b * N * D + e;
  for (int m = tid; m < (N >> 1); m += 256) {
    ob[(size_t)(2 * m) * D]     = re[m] * scale;
    ob[(size_t)(2 * m + 1) * D] = im[m] * scale;
  }
}

extern "C" void kernel_launch(void* const* d_in, const int* in_sizes, int n_in,
                              void* d_out, int out_size, void* d_ws, size_t ws_size,
                              hipStream_t stream) {
  const float* x  = (const float*)d_in[0];
  const float* fl = (const float*)d_in[1];
  const float* Mp = (const float*)d_in[2];
  const float* Mm = (const float*)d_in[3];
  float* out = (float*)d_out;

  const size_t uf_n   = (size_t)B * F_TOT * D;   // float2
  const size_t vf_n   = (size_t)F_TOT * K;       // float2
  const size_t slab_n = (size_t)B * F_TOT * D;   // float2 per G slab
  const size_t mt_b   = (size_t)2 * D * KD * sizeof(__bf16);

  // K-split 2 (4 slabs) if workspace allows, else 1 (2 slabs).
  const size_t need2 = (uf_n + vf_n + 4 * slab_n) * sizeof(float2) + mt_b;
  const int KS = (ws_size >= need2) ? 2 : 1;

  float2* Uf = (float2*)d_ws;
  float2* Vf = Uf + uf_n;
  float2* Gp = Vf + vf_n;
  __bf16* Mt = (__bf16*)(Gp + (size_t)2 * KS * slab_n);

  fwd_fft<<<B * D + K + 32, 256, 0, stream>>>(x, fl, Mp, Mm, Uf, Vf, Mt);
  middle_mfma<<<dim3(128, 2, KS), 256, 0, stream>>>(Uf, Vf, Mt, Gp, KS);
  inv_fft<<<B * D, 256, 0, stream>>>(Gp, Uf, Vf, Mp, Mm, out, 2 * KS);
}

// Round 4
// 211.857 us; speedup vs baseline: 4.1283x; 1.1003x over previous
//
#include <hip/hip_runtime.h>

#define N2   8192
#define N    4096
#define LOGN 12
#define F_TOT 4097   // N2/2 + 1
#define FP    4104   // padded f-stride (float2) for Gt rows (64B row alignment)
#define D    128
#define K    16
#define B    2
#define KD   (K * D)
#define PI_F 3.14159265358979323846f

typedef __bf16 bf16x8 __attribute__((ext_vector_type(8)));
typedef float  f32x4  __attribute__((ext_vector_type(4)));

// LDS index swizzle: spreads bit-reversed write patterns across banks.
// Bijective (XOR of low-5 bits with a function of bits >=6).
__device__ __forceinline__ int swz(int w, bool on) {
  return on ? (w ^ ((w >> 6) & 31)) : w;
}

// In-place radix-2 DIT FFT on bit-reverse-loaded data in LDS.
template<bool SWZ>
__device__ __forceinline__ void fft_lds(float* re, float* im, int tid, int nthr, float sign) {
  for (int s = 0; s < LOGN; ++s) {
    int len = 1 << s;
    for (int t = tid; t < (N >> 1); t += nthr) {
      int j = t & (len - 1);
      int base = ((t >> s) << (s + 1)) + j;
      int i0 = swz(base, SWZ), i1 = swz(base + len, SWZ);
      float ang = sign * PI_F * (float)j / (float)len;
      float wi, wr;
      __sincosf(ang, &wi, &wr);
      float ar = re[i0], ai = im[i0];
      float br = re[i1], bi = im[i1];
      float tr = wr * br - wi * bi;
      float ti = wr * bi + wi * br;
      re[i0] = ar + tr;  im[i0] = ai + ti;
      re[i1] = ar - tr;  im[i1] = ai - ti;
    }
    __syncthreads();
  }
}

// Forward rfft(n=8192) of real length-4096 signals via 4096-pt complex FFT.
// Blocks 0..255: x (b,d). 256..271: filters (k). 272..303: M->bf16 transpose.
__global__ __launch_bounds__(512) void fwd_fft(const float* __restrict__ x,
                                               const float* __restrict__ filt,
                                               const float* __restrict__ Mp,
                                               const float* __restrict__ Mm,
                                               float2* __restrict__ Uf,
                                               float2* __restrict__ Vf,
                                               __bf16* __restrict__ Mt) {
  __shared__ float re[N];
  __shared__ float im[N];
  const int tid = threadIdx.x;
  const int sig = blockIdx.x;

  if (sig >= B * D + K) {          // ---- M prep path ----
    const int pid = sig - (B * D + K);
    const int k = pid & 15, h = pid >> 4;
    const float* src = (h ? Mm : Mp) + (size_t)k * D * D;
    __bf16* dst = Mt + (size_t)h * D * KD;
    for (int d0 = 0; d0 < D; d0 += 16) {
      for (int i = tid; i < 16 * D; i += 512) re[i] = src[(size_t)d0 * D + i];
      __syncthreads();
      if (tid < 256) {
        const int e = tid >> 1, c0 = (tid & 1) * 8;
        bf16x8 w;
#pragma unroll
        for (int j = 0; j < 8; ++j) w[j] = (__bf16)re[(c0 + j) * D + e];
        *(bf16x8*)(dst + (size_t)e * KD + k * D + d0 + c0) = w;
      }
      __syncthreads();
    }
    return;
  }

  const float* in; int istride; float2* outp; int ostride;
  if (sig < B * D) {
    int b = sig >> 7, d = sig & (D - 1);
    in = x + (size_t)b * N * D + d;              istride = D;
    outp = Uf + (size_t)b * F_TOT * D + d;       ostride = D;
  } else {
    int k = sig - B * D;
    in = filt + k;                               istride = K;
    outp = Vf + k;                               ostride = K;
  }
  for (int i = tid; i < N; i += 512) {
    int m = __brev(i) >> (32 - LOGN);
    float vr = 0.f, vi = 0.f;
    if (m < (N >> 1)) {
      vr = in[(size_t)(2 * m) * istride];
      vi = in[(size_t)(2 * m + 1) * istride];
    }
    re[i] = vr; im[i] = vi;
  }
  __syncthreads();
  fft_lds<false>(re, im, tid, 512, -1.0f);
  for (int f = tid; f <= N; f += 512) {
    int f2 = f & (N - 1);
    int fn = (N - f) & (N - 1);
    float zr = re[f2], zi = im[f2];
    float nr = re[fn], ni = im[fn];
    float Er = 0.5f * (zr + nr), Ei = 0.5f * (zi - ni);
    float Or = 0.5f * (zi + ni), Oi = -0.5f * (zr - nr);
    float ang = -PI_F * (float)f / (float)N;
    float wi, wr; __sincosf(ang, &wi, &wr);
    outp[(size_t)f * ostride] = make_float2(Er + wr * Or - wi * Oi,
                                            Ei + wr * Oi + wi * Or);
  }
}

// MFMA middle: rows r = f*4 + b*2 + comp. Wave = 32 rows (8 f) x 128 cols.
// Block = 4 waves = 32 f. Grid (129, half, ks): f-block 128 computes the
// f=4096 edge row (A reads clamped, stores gated to f<F_TOT).
// Output layout TRANSPOSED for inv_fft: Gt[((part*B+b)*D + e)*FP + f].
__global__ __launch_bounds__(256, 2) void middle_mfma(const float2* __restrict__ Uf,
                                                      const float2* __restrict__ Vf,
                                                      const __bf16* __restrict__ Mt,
                                                      float2* __restrict__ Gt,
                                                      int nks) {
  const int tid = threadIdx.x;
  const int l = tid & 63, wave = tid >> 6;
  const int half = blockIdx.y, ks = blockIdx.z;
  const int fw0 = blockIdx.x * 32 + wave * 8;
  const int rowsub = l & 15, g = l >> 4;
  const int fo = rowsub >> 2, bb = (rowsub >> 1) & 1, comp = rowsub & 1;
  int f0s = fw0 + fo;      if (f0s > N) f0s = N;
  int f1s = fw0 + fo + 4;  if (f1s > N) f1s = N;

  const float4* u0p = (const float4*)(Uf + ((size_t)bb * F_TOT + f0s) * D);
  const float4* u1p = (const float4*)(Uf + ((size_t)bb * F_TOT + f1s) * D);
  const float2* v0p = Vf + (size_t)(half ? N - f0s : f0s) * K;
  const float2* v1p = Vf + (size_t)(half ? N - f1s : f1s) * K;
  const float vsgn = half ? -1.f : 1.f;
  const __bf16* mtb = Mt + (size_t)half * D * KD + (size_t)rowsub * KD;

  f32x4 acc[2][8];
#pragma unroll
  for (int s = 0; s < 2; ++s)
#pragma unroll
    for (int nt = 0; nt < 8; ++nt) acc[s][nt] = (f32x4)0.f;

  const int nk = K / nks;
  for (int k8 = 0; k8 < nk; ++k8) {
    const int k = ks * nk + k8;
    float2 v0 = v0p[k], v1 = v1p[k];
    float vi0 = vsgn * v0.y, vi1 = vsgn * v1.y;
    const float c00 = comp ? vi0 : v0.x;
    const float c01 = comp ? v0.x : -vi0;
    const float c10 = comp ? vi1 : v1.x;
    const float c11 = comp ? v1.x : -vi1;
#pragma unroll
    for (int ds = 0; ds < 4; ++ds) {
      const int q = ds * 16 + g * 4;
      float4 ua = u0p[q], ub = u0p[q + 1], uc = u0p[q + 2], ud = u0p[q + 3];
      bf16x8 a0, a1;
      a0[0] = (__bf16)fmaf(c01, ua.y, c00 * ua.x);
      a0[1] = (__bf16)fmaf(c01, ua.w, c00 * ua.z);
      a0[2] = (__bf16)fmaf(c01, ub.y, c00 * ub.x);
      a0[3] = (__bf16)fmaf(c01, ub.w, c00 * ub.z);
      a0[4] = (__bf16)fmaf(c01, uc.y, c00 * uc.x);
      a0[5] = (__bf16)fmaf(c01, uc.w, c00 * uc.z);
      a0[6] = (__bf16)fmaf(c01, ud.y, c00 * ud.x);
      a0[7] = (__bf16)fmaf(c01, ud.w, c00 * ud.z);
      ua = u1p[q]; ub = u1p[q + 1]; uc = u1p[q + 2]; ud = u1p[q + 3];
      a1[0] = (__bf16)fmaf(c11, ua.y, c10 * ua.x);
      a1[1] = (__bf16)fmaf(c11, ua.w, c10 * ua.z);
      a1[2] = (__bf16)fmaf(c11, ub.y, c10 * ub.x);
      a1[3] = (__bf16)fmaf(c11, ub.w, c10 * ub.z);
      a1[4] = (__bf16)fmaf(c11, uc.y, c10 * uc.x);
      a1[5] = (__bf16)fmaf(c11, uc.w, c10 * uc.z);
      a1[6] = (__bf16)fmaf(c11, ud.y, c10 * ud.x);
      a1[7] = (__bf16)fmaf(c11, ud.w, c10 * ud.z);
      const __bf16* bp = mtb + k * D + ds * 32 + g * 8;
#pragma unroll
      for (int nt = 0; nt < 8; ++nt) {
        bf16x8 bf = *(const bf16x8*)(bp + (size_t)nt * 16 * KD);
        acc[0][nt] = __builtin_amdgcn_mfma_f32_16x16x32_bf16(a0, bf, acc[0][nt], 0, 0, 0);
        acc[1][nt] = __builtin_amdgcn_mfma_f32_16x16x32_bf16(a1, bf, acc[1][nt], 0, 0, 0);
      }
    }
  }

  const int part = half * nks + ks;
#pragma unroll
  for (int s = 0; s < 2; ++s) {
    const int fst = fw0 + s * 4 + g;
    if (fst < F_TOT) {
#pragma unroll
      for (int nt = 0; nt < 8; ++nt) {
        const int e = nt * 16 + rowsub;
        Gt[(((size_t)part * B + 0) * D + e) * FP + fst] = make_float2(acc[s][nt][0], acc[s][nt][1]);
        Gt[(((size_t)part * B + 1) * D + e) * FP + fst] = make_float2(acc[s][nt][2], acc[s][nt][3]);
      }
    }
  }
}

// irfft(n=8192) per (b,e): coalesced row reads of Gt (each f once, via
// (kk, N-kk) pairs sharing one twiddle), swizzled LDS, 512 threads.
__global__ __launch_bounds__(512) void inv_fft(const float2* __restrict__ Gt,
                                               float* __restrict__ out, int nslab) {
  __shared__ float re[N];
  __shared__ float im[N];
  const int tid = threadIdx.x;
  const int sig = blockIdx.x;
  const int b = sig >> 7, e = sig & (D - 1);
  const float2* g0 = Gt + ((size_t)b * D + e) * FP;
  const size_t pstr = (size_t)B * D * FP;

  for (int kk = tid; kk <= (N >> 1); kk += 512) {
    float2 Xk = make_float2(0.f, 0.f), Xn = make_float2(0.f, 0.f);
    for (int p = 0; p < nslab; ++p) {
      float2 t1 = g0[p * pstr + kk];
      float2 t2 = g0[p * pstr + (N - kk)];
      Xk.x += t1.x; Xk.y += t1.y;
      Xn.x += t2.x; Xn.y += t2.y;
    }
    float Er = 0.5f * (Xk.x + Xn.x), Ei = 0.5f * (Xk.y - Xn.y);
    float Dr = 0.5f * (Xk.x - Xn.x), Di = 0.5f * (Xk.y + Xn.y);
    float ang = PI_F * (float)kk / (float)N;
    float wi, wr; __sincosf(ang, &wi, &wr);
    float Or = Dr * wr - Di * wi;
    float Oi = Dr * wi + Di * wr;
    int d1 = swz(__brev(kk) >> (32 - LOGN), true);
    re[d1] = Er - Oi; im[d1] = Ei + Or;
    if (kk != 0 && kk != (N >> 1)) {
      int d2 = swz(__brev(N - kk) >> (32 - LOGN), true);
      re[d2] = Er + Oi; im[d2] = -Ei + Or;   // conj-pair: same twiddle
    }
  }
  __syncthreads();
  fft_lds<true>(re, im, tid, 512, +1.0f);
  const float scale = 1.0f / (float)N;
  float* ob = out + (size_t)b * N * D + e;
  for (int m = tid; m < (N >> 1); m += 512) {
    int i0 = swz(m, true);
    ob[(size_t)(2 * m) * D]     = re[i0] * scale;
    ob[(size_t)(2 * m + 1) * D] = im[i0] * scale;
  }
}

extern "C" void kernel_launch(void* const* d_in, const int* in_sizes, int n_in,
                              void* d_out, int out_size, void* d_ws, size_t ws_size,
                              hipStream_t stream) {
  const float* x  = (const float*)d_in[0];
  const float* fl = (const float*)d_in[1];
  const float* Mp = (const float*)d_in[2];
  const float* Mm = (const float*)d_in[3];
  float* out = (float*)d_out;

  const size_t uf_n   = (size_t)B * F_TOT * D;   // float2
  const size_t vf_n   = (size_t)F_TOT * K;       // float2
  const size_t gsl_n  = (size_t)B * D * FP;      // float2 per G slab (transposed)
  const size_t mt_b   = (size_t)2 * D * KD * sizeof(__bf16);

  const size_t need2 = (uf_n + vf_n + 4 * gsl_n) * sizeof(float2) + mt_b;
  const int KS = (ws_size >= need2) ? 2 : 1;

  float2* Uf = (float2*)d_ws;
  float2* Vf = Uf + uf_n;
  float2* Gt = Vf + vf_n;
  __bf16* Mt = (__bf16*)(Gt + (size_t)2 * KS * gsl_n);

  fwd_fft<<<B * D + K + 32, 512, 0, stream>>>(x, fl, Mp, Mm, Uf, Vf, Mt);
  middle_mfma<<<dim3(129, 2, KS), 256, 0, stream>>>(Uf, Vf, Mt, Gt, KS);
  inv_fft<<<B * D, 512, 0, stream>>>(Gt, out, 2 * KS);
}

// Round 5
// 111.478 us; speedup vs baseline: 7.8455x; 1.9004x over previous
//
#include <hip/hip_runtime.h>

#define N2   8192
#define N    4096
#define LOGN 12
#define F_TOT 4097   // N2/2 + 1
#define FP    4112   // padded f-stride (float2) = 257*16
#define D    128
#define K    16
#define B    2
#define KD   (K * D)
#define PI_F 3.14159265358979323846f

typedef __bf16 bf16x8 __attribute__((ext_vector_type(8)));
typedef float  f32x4  __attribute__((ext_vector_type(4)));

// LDS index swizzle for FFT bit-reverse patterns.
__device__ __forceinline__ int swz(int w, bool on) {
  return on ? (w ^ ((w >> 6) & 31)) : w;
}

// In-place radix-2 DIT FFT on bit-reverse-loaded data in LDS.
template<bool SWZ>
__device__ __forceinline__ void fft_lds(float* re, float* im, int tid, int nthr, float sign) {
  for (int s = 0; s < LOGN; ++s) {
    int len = 1 << s;
    for (int t = tid; t < (N >> 1); t += nthr) {
      int j = t & (len - 1);
      int base = ((t >> s) << (s + 1)) + j;
      int i0 = swz(base, SWZ), i1 = swz(base + len, SWZ);
      float ang = sign * PI_F * (float)j / (float)len;
      float wi, wr;
      __sincosf(ang, &wi, &wr);
      float ar = re[i0], ai = im[i0];
      float br = re[i1], bi = im[i1];
      float tr = wr * br - wi * bi;
      float ti = wr * bi + wi * br;
      re[i0] = ar + tr;  im[i0] = ai + ti;
      re[i1] = ar - tr;  im[i1] = ai - ti;
    }
    __syncthreads();
  }
}

// Forward rfft(n=8192) of real length-4096 signals via 4096-pt complex FFT.
// Blocks 0..255: x (b,d). 256..271: filters (k). 272..303: M->bf16 re-layout
// Mt[half][kd8][e][8] with kd8 = k*16 + d/8 (lane-contiguous B-frag loads).
__global__ __launch_bounds__(512) void fwd_fft(const float* __restrict__ x,
                                               const float* __restrict__ filt,
                                               const float* __restrict__ Mp,
                                               const float* __restrict__ Mm,
                                               float2* __restrict__ Uf,
                                               float2* __restrict__ Vf,
                                               __bf16* __restrict__ Mt) {
  __shared__ float re[N];
  __shared__ float im[N];
  const int tid = threadIdx.x;
  const int sig = blockIdx.x;

  if (sig >= B * D + K) {          // ---- M prep path ----
    const int pid = sig - (B * D + K);
    const int k = pid & 15, h = pid >> 4;
    const float* src = (h ? Mm : Mp) + (size_t)k * D * D;
    for (int d0 = 0; d0 < D; d0 += 16) {
      for (int i = tid; i < 16 * D; i += 512) re[i] = src[(size_t)d0 * D + i];
      __syncthreads();
      if (tid < 256) {
        const int e = tid >> 1, c0 = (tid & 1) * 8;
        bf16x8 w;
#pragma unroll
        for (int j = 0; j < 8; ++j) w[j] = (__bf16)re[(c0 + j) * D + e];
        const size_t kd8 = (size_t)h * 256 + k * 16 + ((d0 + c0) >> 3);
        *(bf16x8*)(Mt + (kd8 * D + e) * 8) = w;
      }
      __syncthreads();
    }
    return;
  }

  const float* in; int istride; float2* outp; int ostride;
  if (sig < B * D) {
    int b = sig >> 7, d = sig & (D - 1);
    in = x + (size_t)b * N * D + d;              istride = D;
    outp = Uf + (size_t)b * F_TOT * D + d;       ostride = D;
  } else {
    int k = sig - B * D;
    in = filt + k;                               istride = K;
    outp = Vf + k;                               ostride = K;
  }
  for (int i = tid; i < N; i += 512) {
    int m = __brev(i) >> (32 - LOGN);
    float vr = 0.f, vi = 0.f;
    if (m < (N >> 1)) {
      vr = in[(size_t)(2 * m) * istride];
      vi = in[(size_t)(2 * m + 1) * istride];
    }
    re[i] = vr; im[i] = vi;
  }
  __syncthreads();
  fft_lds<false>(re, im, tid, 512, -1.0f);
  for (int f = tid; f <= N; f += 512) {
    int f2 = f & (N - 1);
    int fn = (N - f) & (N - 1);
    float zr = re[f2], zi = im[f2];
    float nr = re[fn], ni = im[fn];
    float Er = 0.5f * (zr + nr), Ei = 0.5f * (zi - ni);
    float Or = 0.5f * (zi + ni), Oi = -0.5f * (zr - nr);
    float ang = -PI_F * (float)f / (float)N;
    float wi, wr; __sincosf(ang, &wi, &wr);
    outp[(size_t)f * ostride] = make_float2(Er + wr * Or - wi * Oi,
                                            Ei + wr * Oi + wi * Or);
  }
}

// MFMA middle. Wave = one 16-row subtile (4 f x {b,comp}) x 128 e.
// Block = 4 waves = 16 f. Grid (257, half, NKS). u hoisted per-ds, V coeffs
// preloaded, Mt loads lane-contiguous, LDS-transpose epilogue for coalesced
// Gt stores. Gt[((part*B+b)*D + e)*FP + f], part = half*NKS + ks.
template<int NKS>
__global__ __launch_bounds__(256, 4) void middle_mfma(const float2* __restrict__ Uf,
                                                      const float2* __restrict__ Vf,
                                                      const __bf16* __restrict__ Mt,
                                                      float2* __restrict__ Gt) {
  __shared__ float tr_re[256 * 17];
  __shared__ float tr_im[256 * 17];
  const int tid = threadIdx.x;
  const int l = tid & 63, wave = tid >> 6;
  const int half = blockIdx.y, ks = blockIdx.z;
  const int fw0 = blockIdx.x * 16 + wave * 4;
  const int rowsub = l & 15, g = l >> 4;
  const int fo = rowsub >> 2, bb = (rowsub >> 1) & 1, comp = rowsub & 1;
  int fs = fw0 + fo; if (fs > N) fs = N;

  const float4* up = (const float4*)(Uf + ((size_t)bb * F_TOT + fs) * D);
  const float2* vp = Vf + (size_t)(half ? N - fs : fs) * K;
  const float vsgn = half ? -1.f : 1.f;

  constexpr int NK = K / NKS;
  float c0[NK], c1[NK];
#pragma unroll
  for (int k8 = 0; k8 < NK; ++k8) {
    float2 v = vp[ks * NK + k8];
    float vi = vsgn * v.y;
    c0[k8] = comp ? vi : v.x;
    c1[k8] = comp ? v.x : -vi;
  }

  f32x4 acc[8];
#pragma unroll
  for (int nt = 0; nt < 8; ++nt) acc[nt] = (f32x4)0.f;

  // element base: ((half*256 + (ks*NK)*16)*128 + rowsub)*8
  const __bf16* mtb = Mt + (((size_t)half * 256 + (size_t)ks * NK * 16) * D + rowsub) * 8;

#pragma unroll
  for (int ds = 0; ds < 4; ++ds) {
    const int q = ds * 16 + g * 4;
    const float4 ua = up[q], ub = up[q + 1], uc = up[q + 2], ud = up[q + 3];
#pragma unroll
    for (int k8 = 0; k8 < NK; ++k8) {
      bf16x8 a;
      a[0] = (__bf16)fmaf(c1[k8], ua.y, c0[k8] * ua.x);
      a[1] = (__bf16)fmaf(c1[k8], ua.w, c0[k8] * ua.z);
      a[2] = (__bf16)fmaf(c1[k8], ub.y, c0[k8] * ub.x);
      a[3] = (__bf16)fmaf(c1[k8], ub.w, c0[k8] * ub.z);
      a[4] = (__bf16)fmaf(c1[k8], uc.y, c0[k8] * uc.x);
      a[5] = (__bf16)fmaf(c1[k8], uc.w, c0[k8] * uc.z);
      a[6] = (__bf16)fmaf(c1[k8], ud.y, c0[k8] * ud.x);
      a[7] = (__bf16)fmaf(c1[k8], ud.w, c0[k8] * ud.z);
      const __bf16* bp = mtb + ((size_t)(k8 * 16 + ds * 4 + g) * D) * 8;
#pragma unroll
      for (int nt = 0; nt < 8; ++nt) {
        bf16x8 bf = *(const bf16x8*)(bp + nt * 16 * 8);
        acc[nt] = __builtin_amdgcn_mfma_f32_16x16x32_bf16(a, bf, acc[nt], 0, 0, 0);
      }
    }
  }

  // ---- epilogue: transpose via LDS so stores are 128B-contiguous per 16 lanes
  const int fidx = wave * 4 + g;
#pragma unroll
  for (int nt = 0; nt < 8; ++nt) {
    const int e = nt * 16 + rowsub;
    tr_re[e * 17 + fidx]         = acc[nt][0];
    tr_im[e * 17 + fidx]         = acc[nt][1];
    tr_re[(128 + e) * 17 + fidx] = acc[nt][2];
    tr_im[(128 + e) * 17 + fidx] = acc[nt][3];
  }
  __syncthreads();
  const int part = half * NKS + ks;
  const int rrow = tid >> 4;     // 16 rows per iter
  const int rf   = tid & 15;
  float2* gbase = Gt + (size_t)part * B * D * FP + (size_t)blockIdx.x * 16;
#pragma unroll
  for (int it = 0; it < 16; ++it) {
    const int row = it * 16 + rrow;   // row = b*128 + e
    gbase[(size_t)row * FP + rf] = make_float2(tr_re[row * 17 + rf],
                                               tr_im[row * 17 + rf]);
  }
}

// irfft(n=8192) per (b,e): coalesced row reads of Gt, (kk, N-kk) pairs share
// one twiddle, swizzled LDS, 512 threads.
__global__ __launch_bounds__(512) void inv_fft(const float2* __restrict__ Gt,
                                               float* __restrict__ out, int nslab) {
  __shared__ float re[N];
  __shared__ float im[N];
  const int tid = threadIdx.x;
  const int sig = blockIdx.x;
  const int b = sig >> 7, e = sig & (D - 1);
  const float2* g0 = Gt + ((size_t)b * D + e) * FP;
  const size_t pstr = (size_t)B * D * FP;

  for (int kk = tid; kk <= (N >> 1); kk += 512) {
    float2 Xk = make_float2(0.f, 0.f), Xn = make_float2(0.f, 0.f);
    for (int p = 0; p < nslab; ++p) {
      float2 t1 = g0[p * pstr + kk];
      float2 t2 = g0[p * pstr + (N - kk)];
      Xk.x += t1.x; Xk.y += t1.y;
      Xn.x += t2.x; Xn.y += t2.y;
    }
    float Er = 0.5f * (Xk.x + Xn.x), Ei = 0.5f * (Xk.y - Xn.y);
    float Dr = 0.5f * (Xk.x - Xn.x), Di = 0.5f * (Xk.y + Xn.y);
    float ang = PI_F * (float)kk / (float)N;
    float wi, wr; __sincosf(ang, &wi, &wr);
    float Or = Dr * wr - Di * wi;
    float Oi = Dr * wi + Di * wr;
    int d1 = swz(__brev(kk) >> (32 - LOGN), true);
    re[d1] = Er - Oi; im[d1] = Ei + Or;
    if (kk != 0 && kk != (N >> 1)) {
      int d2 = swz(__brev(N - kk) >> (32 - LOGN), true);
      re[d2] = Er + Oi; im[d2] = -Ei + Or;   // conj-pair: same twiddle
    }
  }
  __syncthreads();
  fft_lds<true>(re, im, tid, 512, +1.0f);
  const float scale = 1.0f / (float)N;
  float* ob = out + (size_t)b * N * D + e;
  for (int m = tid; m < (N >> 1); m += 512) {
    int i0 = swz(m, true);
    ob[(size_t)(2 * m) * D]     = re[i0] * scale;
    ob[(size_t)(2 * m + 1) * D] = im[i0] * scale;
  }
}

extern "C" void kernel_launch(void* const* d_in, const int* in_sizes, int n_in,
                              void* d_out, int out_size, void* d_ws, size_t ws_size,
                              hipStream_t stream) {
  const float* x  = (const float*)d_in[0];
  const float* fl = (const float*)d_in[1];
  const float* Mp = (const float*)d_in[2];
  const float* Mm = (const float*)d_in[3];
  float* out = (float*)d_out;

  const size_t uf_n  = (size_t)B * F_TOT * D;   // float2
  const size_t vf_n  = (size_t)F_TOT * K;       // float2
  const size_t gsl_n = (size_t)B * D * FP;      // float2 per G slab
  const size_t mt_b  = (size_t)2 * D * KD * sizeof(__bf16);

  const size_t need2 = (uf_n + vf_n + 4 * gsl_n) * sizeof(float2) + mt_b;
  const int KS = (ws_size >= need2) ? 2 : 1;

  float2* Uf = (float2*)d_ws;
  float2* Vf = Uf + uf_n;
  float2* Gt = Vf + vf_n;
  __bf16* Mt = (__bf16*)(Gt + (size_t)2 * KS * gsl_n);

  fwd_fft<<<B * D + K + 32, 512, 0, stream>>>(x, fl, Mp, Mm, Uf, Vf, Mt);
  if (KS == 2)
    middle_mfma<2><<<dim3(257, 2, 2), 256, 0, stream>>>(Uf, Vf, Mt, Gt);
  else
    middle_mfma<1><<<dim3(257, 2, 1), 256, 0, stream>>>(Uf, Vf, Mt, Gt);
  inv_fft<<<B * D, 512, 0, stream>>>(Gt, out, 2 * KS);
}